// Round 3
// baseline (56.866 us; speedup 1.0000x reference)
//
#include <hip/hip_runtime.h>
#include <math.h>

// ToRGB: y[b,o,p] = clip( sum_i coeff[b,o,i]*x[b,i,p] + bias[o], +-256 ) + upsample2(skip)
// x: (8,512,128,128) f32; out: (8,3,128,128) f32
// coeff[b,o,i] = weight[o,i]/512 * lrelu(w[b,:]@affine_w[i,:]/sqrt(512) + affine_b[i]) * sqrt(2)

#define IN_CH 512
#define OUT_CH 3
#define NPIX 16384    // 128*128
#define NB 8

// ---------------- Kernel 1: styles -> coeff (tiny) ----------------
// grid: 8 batches * 64 row-groups; each block does 8 rows (2 per wave).
__global__ __launch_bounds__(256) void coeff_kernel(
    const float* __restrict__ w, const float* __restrict__ aw,
    const float* __restrict__ ab, const float* __restrict__ wt,
    float* __restrict__ coeff) {
  const int b  = blockIdx.x >> 6;   // 8 batches
  const int rg = blockIdx.x & 63;   // 64 row-groups of 8 rows
  const int tid = threadIdx.x;
  __shared__ float wv[512];
  wv[tid]       = w[b * 512 + tid];
  wv[tid + 256] = w[b * 512 + 256 + tid];
  __syncthreads();
  const int wave = tid >> 6, lane = tid & 63;
  const float gain = 1.0f / sqrtf(512.0f);
  #pragma unroll
  for (int r = 0; r < 2; ++r) {
    const int i = rg * 8 + wave * 2 + r;
    const float* row = aw + (size_t)i * 512;
    float s = 0.f;
    #pragma unroll
    for (int k = 0; k < 8; ++k) s += row[lane + 64 * k] * wv[lane + 64 * k];
    #pragma unroll
    for (int off = 32; off >= 1; off >>= 1) s += __shfl_xor(s, off, 64);
    if (lane == 0) {
      float v = s * gain + ab[i];
      v = (v > 0.f ? v : 0.2f * v) * 1.41421356237f;  // lrelu * sqrt(2)
      #pragma unroll
      for (int o = 0; o < OUT_CH; ++o)
        coeff[b * (OUT_CH * IN_CH) + o * IN_CH + i] =
            wt[o * IN_CH + i] * (1.0f / 512.0f) * v;
    }
  }
}

// ---------------- Kernel 2: main reduction + epilogue ----------------
// grid: 8 batches * 64 pixel-groups (256 px each). block: 256.
// Wave w handles channels w*128..w*128+127; all 64 lanes of a wave load
// 1 KB fully contiguous (float4 * 64 lanes) per channel -> dense HBM requests.
__global__ __launch_bounds__(256) void main_kernel(
    const float* __restrict__ x, const float* __restrict__ coeff,
    const float* __restrict__ bias, const float* __restrict__ skip,
    float* __restrict__ out) {
  const int b   = blockIdx.x >> 6;
  const int g   = blockIdx.x & 63;
  const int p0  = g * 256;
  const int tid = threadIdx.x;
  const int col   = tid & 63;   // float4 column within 256-pixel group
  const int split = tid >> 6;   // == wave id; 128 channels per split

  // coeff staged [split][k][4] -> one wave-uniform ds_read_b128 per k (broadcast)
  __shared__ float lds_c[4 * 128 * 4];  // 8 KB
  for (int idx = tid; idx < 2048; idx += 256) {
    const int s = idx >> 9, rem = idx & 511, k = rem >> 2, o = rem & 3;
    lds_c[idx] = (o < 3)
        ? coeff[b * (OUT_CH * IN_CH) + o * IN_CH + s * 128 + k]
        : 0.f;
  }

  // ---- skip upsample EARLY (hides skip HBM latency under main loop) ----
  // thread t handles pixel p0+t for all 3 output channels
  float up[3];
  {
    const int p = p0 + tid;
    const int yy = p >> 7, xx = p & 127;
    int iy0, ix0; float wy0, wy1, wx0, wx1;
    if (yy & 1) { iy0 = (yy - 1) >> 1; wy0 = 3.f; wy1 = 1.f; }
    else        { iy0 = (yy >> 1) - 1; wy0 = 1.f; wy1 = 3.f; }
    if (xx & 1) { ix0 = (xx - 1) >> 1; wx0 = 3.f; wx1 = 1.f; }
    else        { ix0 = (xx >> 1) - 1; wx0 = 1.f; wx1 = 3.f; }
    const float wyx00 = wy0 * wx0 * (1.f / 16.f), wyx01 = wy0 * wx1 * (1.f / 16.f);
    const float wyx10 = wy1 * wx0 * (1.f / 16.f), wyx11 = wy1 * wx1 * (1.f / 16.f);
    const bool y0ok = (iy0 >= 0), y1ok = (iy0 + 1 < 64);
    const bool x0ok = (ix0 >= 0), x1ok = (ix0 + 1 < 64);
    #pragma unroll
    for (int o = 0; o < OUT_CH; ++o) {
      const float* sp = skip + ((size_t)(b * OUT_CH + o)) * 4096;
      float s00 = (y0ok && x0ok) ? sp[iy0 * 64 + ix0]           : 0.f;
      float s01 = (y0ok && x1ok) ? sp[iy0 * 64 + ix0 + 1]       : 0.f;
      float s10 = (y1ok && x0ok) ? sp[(iy0 + 1) * 64 + ix0]     : 0.f;
      float s11 = (y1ok && x1ok) ? sp[(iy0 + 1) * 64 + ix0 + 1] : 0.f;
      up[o] = wyx00 * s00 + wyx01 * s01 + wyx10 * s10 + wyx11 * s11;
    }
  }

  __syncthreads();

  const float* xp = x + ((size_t)(b * IN_CH + split * 128)) * NPIX + p0 + col * 4;
  const float* cp = lds_c + split * 512;

  float acc[12];
  #pragma unroll
  for (int j = 0; j < 12; ++j) acc[j] = 0.f;

  #pragma unroll 16
  for (int k = 0; k < 128; ++k) {
    float4 xv = *reinterpret_cast<const float4*>(xp + (size_t)k * NPIX);
    float4 c4 = *reinterpret_cast<const float4*>(cp + k * 4);
    acc[0] += c4.x * xv.x; acc[1]  += c4.x * xv.y; acc[2]  += c4.x * xv.z; acc[3]  += c4.x * xv.w;
    acc[4] += c4.y * xv.x; acc[5]  += c4.y * xv.y; acc[6]  += c4.y * xv.z; acc[7]  += c4.y * xv.w;
    acc[8] += c4.z * xv.x; acc[9]  += c4.z * xv.y; acc[10] += c4.z * xv.z; acc[11] += c4.z * xv.w;
  }

  // ---- single-round LDS reduce over the 4 waves ----
  __shared__ float red[4][64][13];  // stride 13: conflict-free
  #pragma unroll
  for (int j = 0; j < 12; ++j) red[split][col][j] = acc[j];
  __syncthreads();

  // epilogue: thread t -> pixel p0+t, 3 channels
  {
    const int c = tid >> 2, s = tid & 3;
    #pragma unroll
    for (int o = 0; o < OUT_CH; ++o) {
      const int j = o * 4 + s;
      float v = red[0][c][j] + red[1][c][j] + red[2][c][j] + red[3][c][j] + bias[o];
      v = fminf(fmaxf(v, -256.f), 256.f);
      out[((size_t)(b * OUT_CH + o)) * NPIX + p0 + tid] = v + up[o];
    }
  }
}

extern "C" void kernel_launch(void* const* d_in, const int* in_sizes, int n_in,
                              void* d_out, int out_size, void* d_ws, size_t ws_size,
                              hipStream_t stream) {
  const float* x        = (const float*)d_in[0];
  const float* w        = (const float*)d_in[1];
  const float* skip     = (const float*)d_in[2];
  const float* affine_w = (const float*)d_in[3];
  const float* affine_b = (const float*)d_in[4];
  const float* weight   = (const float*)d_in[5];
  const float* bias     = (const float*)d_in[6];
  float* out   = (float*)d_out;
  float* coeff = (float*)d_ws;  // 8*3*512 floats = 48 KB

  coeff_kernel<<<512, 256, 0, stream>>>(w, affine_w, affine_b, weight, coeff);
  main_kernel<<<NB * 64, 256, 0, stream>>>(x, coeff, bias, skip, out);
}